// Round 7
// baseline (403.125 us; speedup 1.0000x reference)
//
#include <hip/hip_runtime.h>
#include <stdint.h>

#define DI __device__ __forceinline__

DI float lrelu(float x){ return x >= 0.0f ? x : 0.01f*x; }

// ---------------- threefry2x32, JAX key(42) => (0, 42) ----------------
DI uint32_t rotl32(uint32_t x, int d){ return (x << d) | (x >> (32 - d)); }

DI void threefry_0_42(uint32_t& x0, uint32_t& x1){
  const uint32_t ks0 = 0u, ks1 = 42u, ks2 = 0x1BD11BF0u; // 0 ^ 42 ^ 0x1BD11BDA
  x0 += ks0; x1 += ks1;
  #define TFR(d) { x0 += x1; x1 = rotl32(x1,(d)); x1 ^= x0; }
  TFR(13) TFR(15) TFR(26) TFR(6)  x0 += ks1; x1 += ks2 + 1u;
  TFR(17) TFR(29) TFR(16) TFR(24) x0 += ks2; x1 += ks0 + 2u;
  TFR(13) TFR(15) TFR(26) TFR(6)  x0 += ks0; x1 += ks1 + 3u;
  TFR(17) TFR(29) TFR(16) TFR(24) x0 += ks1; x1 += ks2 + 4u;
  TFR(13) TFR(15) TFR(26) TFR(6)  x0 += ks2; x1 += ks0 + 5u;
  #undef TFR
}

// XLA/Giles single-precision erfinv (same coefficients as chlo erf_inv f32)
DI float erfinv_f32(float x){
  float w = -log1pf(-x*x);
  float p;
  if (w < 5.0f){
    w = w - 2.5f;
    p = 2.81022636e-08f;
    p = fmaf(p, w, 3.43273939e-07f);
    p = fmaf(p, w, -3.5233877e-06f);
    p = fmaf(p, w, -4.39150654e-06f);
    p = fmaf(p, w, 0.00021858087f);
    p = fmaf(p, w, -0.00125372503f);
    p = fmaf(p, w, -0.00417768164f);
    p = fmaf(p, w, 0.246640727f);
    p = fmaf(p, w, 1.50140941f);
  } else {
    w = sqrtf(w) - 3.0f;
    p = -0.000200214257f;
    p = fmaf(p, w, 0.000100950558f);
    p = fmaf(p, w, 0.00134934322f);
    p = fmaf(p, w, -0.00367342844f);
    p = fmaf(p, w, 0.00573950773f);
    p = fmaf(p, w, -0.0076224613f);
    p = fmaf(p, w, 0.00943887047f);
    p = fmaf(p, w, 1.00167406f);
    p = fmaf(p, w, 2.83297682f);
  }
  return p * x;
}

// out offsets (floats)
#define OUT_D_OFF   0
#define OUT_MU_OFF  12288000
#define OUT_LV_OFF  (12288000 + 3840)
#define OUT_Z_OFF   (12288000 + 7680)

// =====================================================================
// enc1: conv(x,w1,SAME 3x3, 6->8)+lrelu+maxpool 2x2 -> p1[32,8,250,64]
__global__ __launch_bounds__(256) void k_enc1(const float* __restrict__ x,
                                              const float* __restrict__ w1,
                                              float* __restrict__ p1){
  __shared__ float tile[6*10*130]; // 7800 floats
  int tid = threadIdx.x;
  int band = blockIdx.x % 63;
  int b    = blockIdx.x / 63;
  int r0 = band*8;
  for (int idx = tid; idx < 6*10*130; idx += 256){
    int lc = idx % 130;
    int rest = idx / 130;
    int lr = rest % 10;
    int ch = rest / 10;
    int gr = r0 - 1 + lr, gc = lc - 1;
    float v = 0.0f;
    if ((unsigned)gr < 500u && (unsigned)gc < 128u)
      v = x[((b*6+ch)*500+gr)*128+gc];
    tile[idx] = v;
  }
  __syncthreads();
  int pw = tid & 63, pr = tid >> 6;
  int ph = band*4 + pr;
  float acc[2][2][8];
  #pragma unroll
  for (int a=0;a<2;a++)
    #pragma unroll
    for (int d=0;d<2;d++)
      #pragma unroll
      for (int o=0;o<8;o++) acc[a][d][o] = 0.0f;
  int base = (2*pr)*130 + 2*pw;
  #pragma unroll 2
  for (int c = 0; c < 6; ++c){
    float win[4][4];
    #pragma unroll
    for (int i=0;i<4;i++)
      #pragma unroll
      for (int j=0;j<4;j++)
        win[i][j] = tile[c*1300 + base + i*130 + j];
    #pragma unroll
    for (int kh=0;kh<3;kh++)
      #pragma unroll
      for (int kw=0;kw<3;kw++){
        float wv[8];
        #pragma unroll
        for (int o=0;o<8;o++) wv[o] = w1[((o*6+c)*3+kh)*3+kw];
        #pragma unroll
        for (int dy=0;dy<2;dy++)
          #pragma unroll
          for (int dx=0;dx<2;dx++){
            float v = win[dy+kh][dx+kw];
            #pragma unroll
            for (int o=0;o<8;o++) acc[dy][dx][o] = fmaf(v, wv[o], acc[dy][dx][o]);
          }
      }
  }
  if (ph < 250){
    #pragma unroll
    for (int o=0;o<8;o++){
      float m = fmaxf(fmaxf(acc[0][0][o], acc[0][1][o]), fmaxf(acc[1][0][o], acc[1][1][o]));
      p1[((b*8+o)*250+ph)*64+pw] = lrelu(m);
    }
  }
}

// =====================================================================
// enc2: conv(p1,w2,SAME 3x3, 8->16)+lrelu+maxpool(5,2) -> p2[32,16,50,32]
// re-split: band = 2 pooled rows (10 conv rows +2 halo) x 64 cols (+2), 8 ch.
// 256 thr = (dx 2) x (pw 32) x (pr 2) x (og 2: 8 och each).
// grid = 25 bands x 32 batch = 800 blocks.
__global__ __launch_bounds__(256) void k_enc2(const float* __restrict__ in,
                                              const float* __restrict__ w2,
                                              float* __restrict__ p2){
  __shared__ float tile[8*12*66]; // 6336 floats
  int tid = threadIdx.x;
  int band = blockIdx.x % 25;
  int b    = blockIdx.x / 25;
  int cr0 = band*10;              // first conv row of band
  for (int idx = tid; idx < 8*12*66; idx += 256){
    int lc = idx % 66;
    int rest = idx / 66;
    int lr = rest % 12;
    int ch = rest / 12;
    int gr = cr0 - 1 + lr, gc = lc - 1;
    float v = 0.0f;
    if ((unsigned)gr < 250u && (unsigned)gc < 64u)
      v = in[((b*8+ch)*250+gr)*64+gc];
    tile[idx] = v;
  }
  __syncthreads();
  int dx = tid & 1;
  int pw = (tid >> 1) & 31;
  int pr = (tid >> 6) & 1;
  int og = tid >> 7;
  int cw = 2*pw + dx;
  int ph = band*2 + pr;           // always < 50
  float acc[5][8];
  #pragma unroll
  for (int dy=0;dy<5;dy++)
    #pragma unroll
    for (int oo=0;oo<8;oo++) acc[dy][oo] = 0.0f;
  int base = (5*pr)*66 + cw;
  #pragma unroll 2
  for (int c = 0; c < 8; ++c){
    float win[7][3];
    #pragma unroll
    for (int i=0;i<7;i++)
      #pragma unroll
      for (int j=0;j<3;j++)
        win[i][j] = tile[c*792 + base + i*66 + j];
    #pragma unroll
    for (int kh=0;kh<3;kh++)
      #pragma unroll
      for (int kw=0;kw<3;kw++){
        float wv[8];
        #pragma unroll
        for (int oo=0;oo<8;oo++) wv[oo] = w2[(((og*8+oo)*8+c)*3+kh)*3+kw];
        #pragma unroll
        for (int dy=0;dy<5;dy++){
          float v = win[dy+kh][kw];
          #pragma unroll
          for (int oo=0;oo<8;oo++) acc[dy][oo] = fmaf(v, wv[oo], acc[dy][oo]);
        }
      }
  }
  #pragma unroll
  for (int oo=0;oo<8;oo++){
    float m = acc[0][oo];
    #pragma unroll
    for (int dy=1;dy<5;dy++) m = fmaxf(m, acc[dy][oo]);
    m = fmaxf(m, __shfl_xor(m, 1));
    if (dx == 0) p2[((b*16+og*8+oo)*50+ph)*32+pw] = lrelu(m);
  }
}

// =====================================================================
// conv3: conv(p2,w3,SAME 3x3, 16->32)+lrelu -> h3[32,32,50,32]
__global__ __launch_bounds__(256) void k_conv3(const float* __restrict__ in,
                                               const float* __restrict__ w3,
                                               float* __restrict__ outp){
  __shared__ float tile[16*10*34]; // 5440 floats
  int tid = threadIdx.x;
  int bi = blockIdx.x;
  int band = bi % 7; int oh = (bi/7) & 1; int b = bi / 14;
  int r0 = band*8;
  for (int idx = tid; idx < 16*10*34; idx += 256){
    int lc = idx % 34;
    int rest = idx / 34;
    int lr = rest % 10;
    int ch = rest / 10;
    int gr = r0 - 1 + lr, gc = lc - 1;
    float v = 0.0f;
    if ((unsigned)gr < 50u && (unsigned)gc < 32u)
      v = in[((b*16+ch)*50+gr)*32+gc];
    tile[idx] = v;
  }
  __syncthreads();
  int col = tid & 31, tr = tid >> 5;
  int h = r0 + tr;
  float acc[16];
  #pragma unroll
  for (int o=0;o<16;o++) acc[o] = 0.0f;
  int base = tr*34 + col;
  #pragma unroll 2
  for (int c = 0; c < 16; ++c){
    float win[3][3];
    #pragma unroll
    for (int i=0;i<3;i++)
      #pragma unroll
      for (int j=0;j<3;j++)
        win[i][j] = tile[c*340 + base + i*34 + j];
    #pragma unroll
    for (int kh=0;kh<3;kh++)
      #pragma unroll
      for (int kw=0;kw<3;kw++){
        float v = win[kh][kw];
        #pragma unroll
        for (int o=0;o<16;o++)
          acc[o] = fmaf(v, w3[(((oh*16+o)*16+c)*3+kh)*3+kw], acc[o]);
      }
  }
  if (h < 50){
    #pragma unroll
    for (int o=0;o<16;o++)
      outp[((b*32 + oh*16 + o)*50 + h)*32 + col] = lrelu(acc[o]);
  }
}

// =====================================================================
// latdec FUSED: pool3 + latent(mu/lv/z + threefry) + dec0 + dec1.
// One block per batch element b (grid = 32).
// h3[b] --pool(5,2)--> p3s LDS --conv(1,5)--> mu/lv --reparam--> z
// --convT(1,5)--> d0s LDS --convT(5,2)--> d1 (global).
__global__ __launch_bounds__(256) void k_latdec(const float* __restrict__ h3,
                                                const float* __restrict__ wmu,
                                                const float* __restrict__ wlv,
                                                const float* __restrict__ wu0,
                                                const float* __restrict__ wu1,
                                                float* __restrict__ outp,
                                                float* __restrict__ d1){
  __shared__ float p3s[5120];    // [c 32][ph 10][pw 16]
  __shared__ float zs[120];
  __shared__ float d0s[5120];    // [o 32][h 10][w 16]
  __shared__ float w1s[10240];   // wu1 copy
  int b = blockIdx.x, tid = threadIdx.x;
  for (int i = tid; i < 10240; i += 256) w1s[i] = wu1[i];
  // ---- pool3 ----
  for (int i = tid; i < 5120; i += 256){
    int pw = i & 15; int u = i >> 4; int ph = u % 10; int c = u / 10;
    const float* src = h3 + ((b*32+c)*50 + 5*ph)*32 + 2*pw;
    float m = -INFINITY;
    #pragma unroll
    for (int dh=0;dh<5;dh++){
      m = fmaxf(m, src[dh*32]);
      m = fmaxf(m, src[dh*32+1]);
    }
    p3s[i] = m;
  }
  __syncthreads();
  // ---- latent ----
  if (tid < 120){
    int w = tid % 12, h = tid / 12;
    float mu = 0.0f, lv = 0.0f;
    for (int c = 0; c < 32; ++c){
      const float* row = p3s + (c*10+h)*16 + w;
      #pragma unroll
      for (int kw=0;kw<5;kw++){
        float v = row[kw];
        mu = fmaf(v, wmu[c*5+kw], mu);
        lv = fmaf(v, wlv[c*5+kw], lv);
      }
    }
    int t = b*120 + tid;
    uint32_t x0 = 0u, x1 = (uint32_t)t;
    threefry_0_42(x0, x1);
    uint32_t bits = x0 ^ x1;
    float f = __uint_as_float((bits >> 9) | 0x3f800000u) - 1.0f;
    const float lo = -0.99999994f;
    float uu = fmaxf(lo, f * 2.0f + lo);
    float eps = 1.41421356f * erfinv_f32(uu);
    float z = mu + eps * expf(0.5f * lv);
    outp[OUT_MU_OFF + t] = mu;
    outp[OUT_LV_OFF + t] = lv;
    outp[OUT_Z_OFF  + t] = z;
    zs[tid] = z;
  }
  __syncthreads();
  // ---- dec0 ----
  for (int i = tid; i < 5120; i += 256){
    int w = i & 15; int u = i >> 4; int h = u % 10; int o = u / 10;
    float a = 0.0f;
    #pragma unroll
    for (int kw=0;kw<5;kw++){
      int ww = w + kw - 4;
      if ((unsigned)ww < 12u) a = fmaf(zs[h*12 + ww], wu0[o*5+kw], a);
    }
    d0s[i] = lrelu(a);
  }
  __syncthreads();
  // ---- dec1 ----
  for (int it = 0; it < 25; ++it){
    int idx = tid + 256*it;  // 6400 = 50*32*4
    int wo = idx & 31; int u = idx >> 5; int ho = u % 50; int og = u / 50;
    int i5 = ho / 5, r = ho - 5*i5, jj = wo >> 1, s = wo & 1;
    float inv[32];
    #pragma unroll
    for (int c=0;c<32;c++) inv[c] = d0s[(c*10+i5)*16 + jj];
    int wb = (4-r)*2 + (1-s);
    #pragma unroll
    for (int oo=0;oo<8;oo++){
      int o = og*8 + oo;
      float a = 0.0f;
      #pragma unroll
      for (int c=0;c<32;c++) a = fmaf(inv[c], w1s[o*320 + c*10 + wb], a);
      d1[((b*32+o)*50+ho)*32+wo] = lrelu(a);
    }
  }
}

// =====================================================================
// c4: conv(d1, w4[16,32,3,3], SAME)+lrelu -> d2[32,16,50,32]
__global__ __launch_bounds__(256) void k_c4(const float* __restrict__ in,
                                            const float* __restrict__ w4,
                                            float* __restrict__ outp){
  __shared__ float tile[32*10*34]; // 10880 floats
  int tid = threadIdx.x;
  int bi = blockIdx.x;
  int band = bi % 7; int oh = (bi/7) & 1; int b = bi / 14;
  int r0 = band*8;
  for (int idx = tid; idx < 32*10*34; idx += 256){
    int lc = idx % 34;
    int rest = idx / 34;
    int lr = rest % 10;
    int ch = rest / 10;
    int gr = r0 - 1 + lr, gc = lc - 1;
    float v = 0.0f;
    if ((unsigned)gr < 50u && (unsigned)gc < 32u)
      v = in[((b*32+ch)*50+gr)*32+gc];
    tile[idx] = v;
  }
  __syncthreads();
  int col = tid & 31, tr = tid >> 5;
  int h = r0 + tr;
  float acc[8];
  #pragma unroll
  for (int o=0;o<8;o++) acc[o] = 0.0f;
  int base = tr*34 + col;
  #pragma unroll 2
  for (int c = 0; c < 32; ++c){
    float win[3][3];
    #pragma unroll
    for (int i=0;i<3;i++)
      #pragma unroll
      for (int j=0;j<3;j++)
        win[i][j] = tile[c*340 + base + i*34 + j];
    #pragma unroll
    for (int kh=0;kh<3;kh++)
      #pragma unroll
      for (int kw=0;kw<3;kw++){
        float v = win[kh][kw];
        #pragma unroll
        for (int o=0;o<8;o++)
          acc[o] = fmaf(v, w4[(((oh*8+o)*32+c)*3+kh)*3+kw], acc[o]);
      }
  }
  if (h < 50){
    #pragma unroll
    for (int o=0;o<8;o++)
      outp[((b*16 + oh*8 + o)*50 + h)*32 + col] = lrelu(acc[o]);
  }
}

// =====================================================================
// u2c5 FUSED: d3 band = convT(d2, wu2, (5,2))+lrelu computed into LDS
// (phase A), then conv(d3, w5[8,16,3,3], SAME)+lrelu -> d4 (phase B).
// d3 tile layout matches old c5: tile[c*660 + lr*66 + lc], lc-1 = global col,
// lr: d3 rows r0-1 .. r0+8. Band = 8 out rows. grid = 32 bands x 32 b.
__global__ __launch_bounds__(256) void k_u2c5(const float* __restrict__ d2,
                                              const float* __restrict__ wu2,
                                              const float* __restrict__ w5,
                                              float* __restrict__ d4out){
  __shared__ float dt[16*10*66];   // 10560 floats, d3 band
  __shared__ float d2s[16*3*32];   // 1536: [cc][di][jj]
  __shared__ float w2s[2560];      // wu2 copy
  int tid = threadIdx.x;
  int band = blockIdx.x & 31;
  int b    = blockIdx.x >> 5;
  int r0 = band*8;
  int i0 = (r0 == 0) ? 0 : (r0-1)/5;
  for (int i = tid; i < 2560; i += 256) w2s[i] = wu2[i];
  for (int idx = tid; idx < 1536; idx += 256){
    int jj = idx & 31; int u = idx >> 5; int di = u % 3; int cc = u / 3;
    int i5 = i0 + di;
    d2s[cc*96 + di*32 + jj] = (i5 < 50) ? d2[((b*16+cc)*50 + i5)*32 + jj] : 0.0f;
  }
  __syncthreads();
  // ---- phase A: build d3 band ----
  for (int s = tid; s < 10560; s += 256){
    int lc = s % 66;
    int u = s / 66;
    int lr = u % 10;
    int c  = u / 10;
    int gc = lc - 1;
    int h  = r0 - 1 + lr;
    float v = 0.0f;
    if ((unsigned)h < 250u && (unsigned)gc < 64u){
      int i5 = h / 5, r = h - 5*i5, jj = gc >> 1, sx = gc & 1;
      int di = i5 - i0;
      const float* dp = d2s + di*32 + jj;          // + cc*96
      const float* wp = w2s + c*160 + (4-r)*2 + (1-sx); // + cc*10
      float a = 0.0f;
      #pragma unroll
      for (int cc=0;cc<16;cc++) a = fmaf(dp[cc*96], wp[cc*10], a);
      v = lrelu(a);
    }
    dt[s] = v;
  }
  __syncthreads();
  // ---- phase B: conv 3x3 16->8 (identical to proven c5 phase) ----
  int cp = tid & 31, tr = tid >> 5;   // cols {2cp, 2cp+1}, row r0+tr
  int h = r0 + tr;
  float acc[2][8];
  #pragma unroll
  for (int dx=0;dx<2;dx++)
    #pragma unroll
    for (int o=0;o<8;o++) acc[dx][o] = 0.0f;
  int base = tr*66 + 2*cp;
  #pragma unroll 2
  for (int c = 0; c < 16; ++c){
    float win[3][4];
    #pragma unroll
    for (int i=0;i<3;i++)
      #pragma unroll
      for (int j=0;j<4;j++)
        win[i][j] = dt[c*660 + base + i*66 + j];
    #pragma unroll
    for (int kh=0;kh<3;kh++)
      #pragma unroll
      for (int kw=0;kw<3;kw++){
        float wv[8];
        #pragma unroll
        for (int o=0;o<8;o++) wv[o] = w5[((o*16+c)*3+kh)*3+kw];
        #pragma unroll
        for (int dx=0;dx<2;dx++){
          float v = win[kh][dx+kw];
          #pragma unroll
          for (int o=0;o<8;o++) acc[dx][o] = fmaf(v, wv[o], acc[dx][o]);
        }
      }
  }
  if (h < 250){
    #pragma unroll
    for (int dx=0;dx<2;dx++)
      #pragma unroll
      for (int o=0;o<8;o++)
        d4out[((b*8+o)*250+h)*64 + 2*cp+dx] = lrelu(acc[dx][o]);
  }
}

// =====================================================================
// u3c6 FUSED: d5 band via convT(d4, wu3, (2,2))+lrelu into LDS (phase A),
// then conv(d5, w6[6,8,3,3], SAME)+lrelu -> out (phase B).
__global__ __launch_bounds__(256) void k_u3c6(const float* __restrict__ d4,
                                              const float* __restrict__ wu3,
                                              const float* __restrict__ w6,
                                              float* __restrict__ outp){
  __shared__ __align__(16) float dt[8*10*132]; // 42240 B
  __shared__ __align__(16) float wl[256];      // wu3 copy
  int tid = threadIdx.x;
  int band = blockIdx.x % 63;
  int b    = blockIdx.x / 63;
  int r0 = band*8;
  wl[tid] = wu3[tid];
  if (tid < 80){
    int ch = tid / 10, lr = tid % 10;
    dt[(ch*10+lr)*132 + 128] = 0.0f;
    dt[(ch*10+lr)*132 + 129] = 0.0f;
  }
  __syncthreads();
  // ---- phase A: build d5 band rows r0-1 .. r0+8 ----
  for (int s = tid; s < 320; s += 256){
    int q = s & 31, lr = s >> 5;
    int h = r0 - 1 + lr;               // d5 row
    if ((unsigned)h < 500u){
      int i2 = h >> 1, r = h & 1;
      float2 dv[8];
      #pragma unroll
      for (int c=0;c<8;c++)
        dv[c] = *(const float2*)(d4 + ((b*8+c)*250 + i2)*64 + 2*q);
      int wbase = (1-r)*2;
      #pragma unroll
      for (int o5=0;o5<8;o5++){
        float a0=0.f,a1=0.f,a2=0.f,a3=0.f;
        #pragma unroll
        for (int c=0;c<8;c++){
          float2 wp = *(const float2*)(wl + o5*32 + c*4 + wbase);
          a0 = fmaf(dv[c].x, wp.y, a0);
          a1 = fmaf(dv[c].x, wp.x, a1);
          a2 = fmaf(dv[c].y, wp.y, a2);
          a3 = fmaf(dv[c].y, wp.x, a3);
        }
        float4 v4 = make_float4(lrelu(a0), lrelu(a1), lrelu(a2), lrelu(a3));
        *(float4*)(dt + (o5*10+lr)*132 + 4*q) = v4;
      }
    } else {
      float4 z = make_float4(0.f,0.f,0.f,0.f);
      #pragma unroll
      for (int o5=0;o5<8;o5++)
        *(float4*)(dt + (o5*10+lr)*132 + 4*q) = z;
    }
  }
  __syncthreads();
  // ---- phase B: conv 3x3 8->6 over the d5 band ----
  int q = tid & 31, tr = tid >> 5;     // cols 4q..4q+3, out row r0+tr
  int R = r0 + tr;
  float acc[4][6];
  #pragma unroll
  for (int j=0;j<4;j++)
    #pragma unroll
    for (int o=0;o<6;o++) acc[j][o] = 0.0f;
  int left = (q==0) ? 129 : (4*q - 1);
  #pragma unroll 2
  for (int ch=0; ch<8; ++ch){
    #pragma unroll
    for (int wr=0; wr<3; ++wr){
      const float* row = dt + (ch*10 + tr + wr)*132;
      float win[6];
      float4 m = *(const float4*)(row + 4*q);
      win[0] = row[left];
      win[1] = m.x; win[2] = m.y; win[3] = m.z; win[4] = m.w;
      win[5] = row[4*q + 4];
      #pragma unroll
      for (int kw=0;kw<3;kw++){
        #pragma unroll
        for (int o=0;o<6;o++){
          float wv = w6[((o*8+ch)*3+wr)*3+kw];
          #pragma unroll
          for (int j=0;j<4;j++)
            acc[j][o] = fmaf(win[j+kw], wv, acc[j][o]);
        }
      }
    }
  }
  if (R < 500){
    #pragma unroll
    for (int o=0;o<6;o++){
      float4 v = make_float4(lrelu(acc[0][o]), lrelu(acc[1][o]),
                             lrelu(acc[2][o]), lrelu(acc[3][o]));
      *(float4*)(outp + ((b*6+o)*500 + R)*128 + 4*q) = v;
    }
  }
}

// =====================================================================
extern "C" void kernel_launch(void* const* d_in, const int* in_sizes, int n_in,
                              void* d_out, int out_size, void* d_ws, size_t ws_size,
                              hipStream_t stream){
  const float* x   = (const float*)d_in[0];
  const float* w1  = (const float*)d_in[1];
  const float* w2  = (const float*)d_in[2];
  const float* w3  = (const float*)d_in[3];
  const float* wmu = (const float*)d_in[4];
  const float* wlv = (const float*)d_in[5];
  const float* wu0 = (const float*)d_in[6];
  const float* wu1 = (const float*)d_in[7];
  const float* w4  = (const float*)d_in[8];
  const float* wu2 = (const float*)d_in[9];
  const float* w5  = (const float*)d_in[10];
  const float* wu3 = (const float*)d_in[11];
  const float* w6  = (const float*)d_in[12];
  float* out = (float*)d_out;
  float* A  = (float*)d_ws;          // 4,096,000 floats arena
  float* Bb = A + 4096000;           // 16,384,000 floats arena

  k_enc1 <<<2016, 256, 0, stream>>>(x,  w1,  A);        // p1 -> A
  k_enc2 <<< 800, 256, 0, stream>>>(A,  w2,  Bb);       // p2 -> Bb
  k_conv3<<< 448, 256, 0, stream>>>(Bb, w3,  A);        // h3 -> A
  k_latdec<<<  32, 256, 0, stream>>>(A, wmu, wlv, wu0, wu1, out, Bb); // mu/lv/z -> out, d1 -> Bb
  k_c4   <<< 448, 256, 0, stream>>>(Bb, w4,  A);        // d2 -> A
  k_u2c5 <<<1024, 256, 0, stream>>>(A,  wu2, w5, Bb);   // d4 -> Bb
  k_u3c6 <<<2016, 256, 0, stream>>>(Bb, wu3, w6, out);  // d  -> out
}